// Round 23
// baseline (1297.789 us; speedup 1.0000x reference)
//
#include <hip/hip_runtime.h>
#include <cmath>

#define HH 48
#define WW 48
#define HWSZ 2304
#define BB 8
#define TT 32
#define PADPX 2688   // 64 guard + 2464 main + 160 guard
#define POFF 64
#define NWAVE 39     // waves of 64 px covering 2464 padded-linear px

typedef unsigned short u16;
typedef __attribute__((ext_vector_type(8))) short bf16x8;
typedef __attribute__((ext_vector_type(4))) float f32x4;
typedef __attribute__((ext_vector_type(4))) short s16x4;

__device__ __forceinline__ u16 f2bf(float f) {
    unsigned int u = __float_as_uint(f);
    u = (u + 0x7fffu + ((u >> 16) & 1u)) >> 16;
    return (u16)u;
}
__device__ __forceinline__ float bf2f(u16 s) {
    return __uint_as_float(((unsigned int)s) << 16);
}
__device__ __forceinline__ float sigm(float x) { return 1.f / (1.f + __expf(-x)); }

// ---------------- weight fragments ----------------
// A frag = 16 hid x 32 k, 1KB; lane: m = lane&15, k = (lane>>4)*8 + j.
// wf frag index space:
//   [0,576)    : L0-h [hidg4][cs2][tap9][g4][pl2]   (w0 ic = cs*32 + k + 1)
//   [576,1008) : L1   [hidg2][cs3][tap9][g4][pl2]   (w1 ic = cs*32 + k)
// wxf (fp32):  [tap9][g4][mblock16][4]  -> w0 ic = 0 (the x channel), m=oc row
// A stays hi+lo split (weight rounding is SYSTEMATIC; reused every step).
// h (the B operand) is single round-to-nearest bf16 (stochastic per step).
__global__ void wprep(const float* __restrict__ w0, const float* __restrict__ w1,
                      u16* __restrict__ wf, float* __restrict__ wxf)
{
    const int gid = blockIdx.x * 256 + threadIdx.x;
    if (gid < 1008 * 64) {
        const int lane = gid & 63;
        const int f = gid >> 6;
        const int m = lane & 15;
        const int kh = lane >> 4;
        float v[8];
        int pl;
        if (f < 576) {
            pl = f & 1;
            const int g = (f >> 1) & 3;
            int r = f >> 3;
            const int tap = r % 9; r /= 9;
            const int cs = r & 1;
            const int hidg = r >> 1;
            const int oc = g * 64 + hidg * 16 + m;
            #pragma unroll
            for (int j = 0; j < 8; ++j) {
                const int ic = cs * 32 + kh * 8 + j + 1;
                v[j] = w0[((size_t)oc * 65 + ic) * 9 + tap];
            }
        } else {
            const int f2 = f - 576;
            pl = f2 & 1;
            const int g = (f2 >> 1) & 3;
            int r = f2 >> 3;
            const int tap = r % 9; r /= 9;
            const int cs = r % 3;
            const int hidg = r / 3;
            const int oc = g * 32 + hidg * 16 + m;
            #pragma unroll
            for (int j = 0; j < 8; ++j) {
                const int ic = cs * 32 + kh * 8 + j;
                v[j] = w1[((size_t)oc * 96 + ic) * 9 + tap];
            }
        }
        u16 o[8] __attribute__((aligned(16)));
        #pragma unroll
        for (int j = 0; j < 8; ++j) {
            const u16 hi = f2bf(v[j]);
            o[j] = pl ? (u16)f2bf(v[j] - bf2f(hi)) : hi;
        }
        *(uint4*)(wf + (size_t)gid * 8) = *(const uint4*)o;
    }
    const int wx = gid - 1008 * 64;
    if (wx >= 0 && wx < 2304) {
        const int e = wx & 3;
        const int f4 = wx >> 2;
        const int mb = f4 & 15;
        const int tg = f4 >> 4;
        const int g = tg & 3;
        const int tap = tg >> 2;
        const int m = mb * 4 + e;
        wxf[wx] = w0[((size_t)(g * 64 + m) * 65 + 0) * 9 + tap];
    }
}

// x padded fp32 plane: [t][b][PADPX], zero guard (buffer memset beforehand).
__global__ void xprep(const float* __restrict__ x, float* __restrict__ xpad)
{
    const int gid = blockIdx.x * 256 + threadIdx.x;
    if (gid >= TT * BB * HWSZ) return;
    const int pix = gid % HWSZ;
    const int b = (gid / HWSZ) % BB;
    const int t = gid / (HWSZ * BB);
    const float v = x[((size_t)b * TT + t) * HWSZ + pix];
    const int y = pix / 48, xx = pix - y * 48;
    const int p = (y + 1) * 50 + (xx + 1);
    xpad[(size_t)(t * BB + b) * PADPX + POFF + p] = v;
}

// One step: L0(t) [units 0..3] and L1(t-1) [units 4..5].
// Block = 256 threads (4 waves); wave = 64 px (4 B-tiles) x 16 hid x 4 gates.
// Per tap: 8 ds_read_b128 feed 32 MFMAs -> MFMA-bound per wave; 72 KB A-slot
// in LDS -> 2 blocks/CU co-resident, so one block's staging/barrier overlaps
// the other's compute (what r21 had and r22 lost).
// c-state first use takes cp=0 via czero flags (no cbuf memset needed).
// h buffers: [kslot6][b][PADPX][16ch], single bf16 (kslot 0-3 = h0, 4-5 = h1).
__global__ __launch_bounds__(256, 2) void mstep(
    const u16* __restrict__ in_hi,
    u16* __restrict__ out_hi,
    const float* __restrict__ xpad,
    const u16* __restrict__ wf, const float* __restrict__ wxf,
    const float* __restrict__ b0, const float* __restrict__ b1,
    float* __restrict__ cbuf, float* __restrict__ seq_t,
    int t, int doL0, int doL1, int c0z, int c1z)
{
    __shared__ __align__(16) char ldsA[73728];   // one 72 KB A-slot

    const int tid = threadIdx.x;
    const int lane = tid & 63;
    const int wv = tid >> 6;         // 0..3
    const int lid = blockIdx.x;
    const int b = lid & 7;           // XCD selector
    const int r = lid >> 3;          // 0..59
    const int unit = r % 6;
    const int pg = r / 6;            // 0..9
    const bool isL0 = unit < 4;
    if (isL0) { if (!doL0) return; } else { if (!doL1) return; }   // block-uniform
    const int frag = pg * 4 + wv;    // 0..39
    const bool active = frag < NWAVE;   // inactive waves still stage + barrier
    const int p0 = (active ? frag : 0) * 64;
    const int hidg = isL0 ? unit : (unit - 4);
    const bool czero = isL0 ? (c0z != 0) : (c1z != 0);

    const int n   = lane & 15;        // px col within tile; also A row m
    const int khb = (lane >> 4) & 1;  // within-slot 8-ch half for B
    const int ksl = lane >> 5;        // slot parity for B
    const int mq  = lane >> 4;        // D row quarter: m = mq*4 + e

    // acc init = bias (D: col=lane&15, row m=mq*4+e)
    const float* bias = isL0 ? b0 : b1;
    const int CHID = isL0 ? 64 : 32;
    f32x4 acc[4][4];                  // [px-tile][gate]
    #pragma unroll
    for (int g = 0; g < 4; ++g) {
        const f32x4 bv = *(const f32x4*)(bias + g * CHID + hidg * 16 + mq * 4);
        #pragma unroll
        for (int tl = 0; tl < 4; ++tl) acc[tl][g] = bv;
    }

    const size_t base0 = ((size_t)(ksl * 8 + b) * PADPX + POFF + p0 + n) * 16 + khb * 8;
    const size_t bstride = (size_t)2 * 8 * PADPX * 16;   // per slot-pair

    const int nsl = isL0 ? 2 : 3;
    const char* pa = ldsA + lane * 16;

    for (int sp = 0; sp < nsl; ++sp) {
        const u16* pbh = in_hi + base0 + (size_t)sp * bstride;
        // pre-issue B(tap 0) so its latency hides under staging + barrier
        bf16x8 Bc0 = *(const bf16x8*)(pbh + (long)(-51) * 16);
        bf16x8 Bc1 = *(const bf16x8*)(pbh + (long)(-35) * 16);
        bf16x8 Bc2 = *(const bf16x8*)(pbh + (long)(-19) * 16);
        bf16x8 Bc3 = *(const bf16x8*)(pbh + (long)(-3) * 16);

        if (sp) __syncthreads();        // previous slot's readers done
        // stage this slot's 72 KB of A fragments (coalesced, linear)
        const u16* asrc = wf + (isL0 ? (size_t)((hidg * 2 + sp) * 72) * 512
                                     : (size_t)(576 + (hidg * 3 + sp) * 72) * 512);
        #pragma unroll
        for (int i = 0; i < 18; ++i) {
            const int u = tid + 256 * i;          // 4608 x 16B units
            *(uint4*)(ldsA + (size_t)u * 16) = *(const uint4*)(asrc + (size_t)u * 8);
        }
        __syncthreads();

        #pragma unroll
        for (int tap = 0; tap < 9; ++tap) {
            bf16x8 Bn0, Bn1, Bn2, Bn3;
            if (tap < 8) {
                const int tap2 = tap + 1;
                const int toff2 = ((tap2 / 3) - 1) * 50 + (tap2 % 3) - 1;
                Bn0 = *(const bf16x8*)(pbh + (long)toff2 * 16);
                Bn1 = *(const bf16x8*)(pbh + (long)(toff2 + 16) * 16);
                Bn2 = *(const bf16x8*)(pbh + (long)(toff2 + 32) * 16);
                Bn3 = *(const bf16x8*)(pbh + (long)(toff2 + 48) * 16);
            }
            #pragma unroll
            for (int g = 0; g < 4; ++g) {
                const bf16x8 Ah = *(const bf16x8*)(pa + (size_t)(tap * 8 + g * 2 + 0) * 1024);
                const bf16x8 Al = *(const bf16x8*)(pa + (size_t)(tap * 8 + g * 2 + 1) * 1024);
                acc[0][g] = __builtin_amdgcn_mfma_f32_16x16x32_bf16(Al, Bc0, acc[0][g], 0, 0, 0);
                acc[1][g] = __builtin_amdgcn_mfma_f32_16x16x32_bf16(Al, Bc1, acc[1][g], 0, 0, 0);
                acc[2][g] = __builtin_amdgcn_mfma_f32_16x16x32_bf16(Al, Bc2, acc[2][g], 0, 0, 0);
                acc[3][g] = __builtin_amdgcn_mfma_f32_16x16x32_bf16(Al, Bc3, acc[3][g], 0, 0, 0);
                acc[0][g] = __builtin_amdgcn_mfma_f32_16x16x32_bf16(Ah, Bc0, acc[0][g], 0, 0, 0);
                acc[1][g] = __builtin_amdgcn_mfma_f32_16x16x32_bf16(Ah, Bc1, acc[1][g], 0, 0, 0);
                acc[2][g] = __builtin_amdgcn_mfma_f32_16x16x32_bf16(Ah, Bc2, acc[2][g], 0, 0, 0);
                acc[3][g] = __builtin_amdgcn_mfma_f32_16x16x32_bf16(Ah, Bc3, acc[3][g], 0, 0, 0);
            }
            if (tap < 8) { Bc0 = Bn0; Bc1 = Bn1; Bc2 = Bn2; Bc3 = Bn3; }
        }
    }

    if (isL0) {
        // ---- x channel on VALU, exact fp32 ----
        const float* xrow = xpad + (size_t)(t * BB + b) * PADPX + POFF + p0 + n;
        #pragma unroll
        for (int tap = 0; tap < 9; ++tap) {
            const int toff = ((tap / 3) - 1) * 50 + (tap % 3) - 1;
            float xv[4];
            #pragma unroll
            for (int tl = 0; tl < 4; ++tl) xv[tl] = xrow[toff + 16 * tl];
            #pragma unroll
            for (int g = 0; g < 4; ++g) {
                const f32x4 wvx = *(const f32x4*)(wxf +
                    ((size_t)(tap * 4 + g) * 16 + hidg * 4 + mq) * 4);
                #pragma unroll
                for (int tl = 0; tl < 4; ++tl)
                    #pragma unroll
                    for (int e = 0; e < 4; ++e)
                        acc[tl][g][e] += wvx[e] * xv[tl];
            }
        }
    }

    if (!active) return;   // no more barriers past this point

    // ---- epilogue: LSTM pointwise; lane owns 4 px (one per tile), 4 m-rows ----
    const int slot = (unit * 8 + b) * NWAVE + frag;
    float* cptr = cbuf + (size_t)slot * 1024;
    #pragma unroll
    for (int tl = 0; tl < 4; ++tl) {
        const f32x4 cp = czero ? (f32x4){0.f, 0.f, 0.f, 0.f}
                               : *(const f32x4*)(cptr + tl * 256 + lane * 4);
        const int p = p0 + tl * 16 + n;
        const int py = p / 50, pxx = p - py * 50;
        const bool valid = (py >= 1) && (py <= 48) && (pxx >= 1) && (pxx <= 48);
        const int pix = (py - 1) * 48 + (pxx - 1);
        const bool doseq = (!isL0) && (b == 0) && valid;
        f32x4 cn;
        s16x4 sh;
        #pragma unroll
        for (int e = 0; e < 4; ++e) {
            const float i_ = sigm(acc[tl][0][e]);
            const float f_ = sigm(acc[tl][1][e]);
            const float o_ = sigm(acc[tl][2][e]);
            const float g_ = tanhf(acc[tl][3][e]);
            const float cv = f_ * cp[e] + i_ * g_;
            const float hv = o_ * tanhf(cv);
            cn[e] = cv;
            sh[e] = (short)f2bf(hv);
            if (doseq) {
                const int ch = hidg * 16 + mq * 4 + e;
                __builtin_nontemporal_store(hv, seq_t + (size_t)ch * HWSZ + pix);
            }
        }
        *(f32x4*)(cptr + tl * 256 + lane * 4) = cn;
        if (valid) {
            const int kslot = (isL0 ? 0 : 4) + hidg;
            const size_t ob = (((size_t)kslot * 8 + b) * PADPX + POFF + p) * 16 + mq * 4;
            *(s16x4*)(out_hi + ob) = sh;
        }
    }
}

// out[k] = bl + sum_j wl[j] * seq_flat[32k+j]   (seq layout [t][32ch][2304px])
__global__ void head_kernel(const float* __restrict__ seq,
                            const float* __restrict__ wl,
                            const float* __restrict__ bl,
                            float* __restrict__ out, int nk)
{
    __shared__ float wls[32];
    if (threadIdx.x < 32) wls[threadIdx.x] = wl[threadIdx.x];
    __syncthreads();
    int k = blockIdx.x * 256 + threadIdx.x;
    if (k >= nk) return;
    const float4* p = (const float4*)(seq + (size_t)k * 32);
    float s = bl[0];
    #pragma unroll
    for (int q = 0; q < 8; ++q) {
        float4 f = p[q];
        s += f.x * wls[q * 4 + 0] + f.y * wls[q * 4 + 1]
           + f.z * wls[q * 4 + 2] + f.w * wls[q * 4 + 3];
    }
    out[k] = s;
}

extern "C" void kernel_launch(void* const* d_in, const int* in_sizes, int n_in,
                              void* d_out, int out_size, void* d_ws, size_t ws_size,
                              hipStream_t stream)
{
    const float* x  = (const float*)d_in[0];   // [8,32,1,48,48]
    const float* w0 = (const float*)d_in[1];   // [256,65,3,3]
    const float* b0 = (const float*)d_in[2];   // [256]
    const float* w1 = (const float*)d_in[3];   // [128,96,3,3]
    const float* b1 = (const float*)d_in[4];   // [128]
    const float* wl = (const float*)d_in[5];   // [1,32]
    const float* bl = (const float*)d_in[6];   // [1]
    float* out = (float*)d_out;                // [73728]

    char* p = (char*)d_ws;
    auto alloc = [&](size_t bytes) -> char* {
        char* r = p; p += (bytes + 255) & ~(size_t)255; return r;
    };
    const size_t inbytes = (size_t)6 * BB * PADPX * 16 * 2;   // 3.94 MB
    u16* inA_hi = (u16*)alloc(inbytes);
    u16* inB_hi = (u16*)alloc(inbytes);
    const size_t xbytes = (size_t)TT * BB * PADPX * 4;        // 2.75 MB
    float* xpad = (float*)alloc(xbytes);
    u16* wfall  = (u16*)alloc((size_t)1008 * 1024);           // 1.03 MB
    float* wxf  = (float*)alloc((size_t)2304 * 4);
    const size_t cbytes = (size_t)6 * BB * NWAVE * 1024 * 4;  // 7.67 MB
    float* cbuf = (float*)alloc(cbytes);
    float* seq  = (float*)alloc((size_t)TT * 32 * HWSZ * 4);  // 9.44 MB

    hipMemsetAsync(inA_hi, 0, inbytes, stream);
    hipMemsetAsync(inB_hi, 0, inbytes, stream);
    hipMemsetAsync(xpad, 0, xbytes, stream);

    wprep<<<(1008 * 64 + 2304 + 255) / 256, 256, 0, stream>>>(w0, w1, wfall, wxf);
    xprep<<<(TT * BB * HWSZ + 255) / 256, 256, 0, stream>>>(x, xpad);

    for (int s = 0; s <= TT; ++s) {
        const u16* cih = (s & 1) ? inB_hi : inA_hi;
        u16* noh = (s & 1) ? inA_hi : inB_hi;
        const int tq = (s >= 1) ? (s - 1) : 0;
        mstep<<<dim3(480), 256, 0, stream>>>(
            cih, noh, xpad, wfall, wxf, b0, b1,
            cbuf, seq + (size_t)tq * 32 * HWSZ,
            (s < TT) ? s : 0, (s < TT) ? 1 : 0, (s >= 1) ? 1 : 0,
            (s == 0) ? 1 : 0, (s == 1) ? 1 : 0);
    }
    head_kernel<<<288, 256, 0, stream>>>(seq, wl, bl, out, 73728);
}

// Round 24
// 1017.623 us; speedup vs baseline: 1.2753x; 1.2753x over previous
//
#include <hip/hip_runtime.h>
#include <cmath>

#define HH 48
#define WW 48
#define HWSZ 2304
#define BB 8
#define TT 32
#define PADPX 2688   // 64 guard + 2464 main + 160 guard
#define POFF 64
#define NWAVE 77     // waves of 32 px covering 2464 padded-linear px

typedef unsigned short u16;
typedef __attribute__((ext_vector_type(8))) short bf16x8;
typedef __attribute__((ext_vector_type(4))) float f32x4;
typedef __attribute__((ext_vector_type(4))) short s16x4;

__device__ __forceinline__ u16 f2bf(float f) {
    unsigned int u = __float_as_uint(f);
    u = (u + 0x7fffu + ((u >> 16) & 1u)) >> 16;
    return (u16)u;
}
__device__ __forceinline__ float bf2f(u16 s) {
    return __uint_as_float(((unsigned int)s) << 16);
}
__device__ __forceinline__ float sigm(float x) { return 1.f / (1.f + __expf(-x)); }

// ---------------- weight fragments ----------------
// A frag = 16 hid x 32 k, 1KB; lane: m = lane&15, k = (lane>>4)*8 + j.
// wf frag index space:
//   [0,576)    : L0-h [hidg4][cs2][tap9][g4][pl2]   (w0 ic = cs*32 + k + 1)
//   [576,1008) : L1   [hidg2][cs3][tap9][g4][pl2]   (w1 ic = cs*32 + k)
// wxf (fp32):  [tap9][g4][mblock16][4]  -> w0 ic = 0 (the x channel), m=oc row
// A stays hi+lo split (weight rounding is SYSTEMATIC; reused every step).
// h (the B operand) is single round-to-nearest bf16 (stochastic per step).
__global__ void wprep(const float* __restrict__ w0, const float* __restrict__ w1,
                      u16* __restrict__ wf, float* __restrict__ wxf)
{
    const int gid = blockIdx.x * 256 + threadIdx.x;
    if (gid < 1008 * 64) {
        const int lane = gid & 63;
        const int f = gid >> 6;
        const int m = lane & 15;
        const int kh = lane >> 4;
        float v[8];
        int pl;
        if (f < 576) {
            pl = f & 1;
            const int g = (f >> 1) & 3;
            int r = f >> 3;
            const int tap = r % 9; r /= 9;
            const int cs = r & 1;
            const int hidg = r >> 1;
            const int oc = g * 64 + hidg * 16 + m;
            #pragma unroll
            for (int j = 0; j < 8; ++j) {
                const int ic = cs * 32 + kh * 8 + j + 1;
                v[j] = w0[((size_t)oc * 65 + ic) * 9 + tap];
            }
        } else {
            const int f2 = f - 576;
            pl = f2 & 1;
            const int g = (f2 >> 1) & 3;
            int r = f2 >> 3;
            const int tap = r % 9; r /= 9;
            const int cs = r % 3;
            const int hidg = r / 3;
            const int oc = g * 32 + hidg * 16 + m;
            #pragma unroll
            for (int j = 0; j < 8; ++j) {
                const int ic = cs * 32 + kh * 8 + j;
                v[j] = w1[((size_t)oc * 96 + ic) * 9 + tap];
            }
        }
        u16 o[8] __attribute__((aligned(16)));
        #pragma unroll
        for (int j = 0; j < 8; ++j) {
            const u16 hi = f2bf(v[j]);
            o[j] = pl ? (u16)f2bf(v[j] - bf2f(hi)) : hi;
        }
        *(uint4*)(wf + (size_t)gid * 8) = *(const uint4*)o;
    }
    const int wx = gid - 1008 * 64;
    if (wx >= 0 && wx < 2304) {
        const int e = wx & 3;
        const int f4 = wx >> 2;
        const int mb = f4 & 15;
        const int tg = f4 >> 4;
        const int g = tg & 3;
        const int tap = tg >> 2;
        const int m = mb * 4 + e;
        wxf[wx] = w0[((size_t)(g * 64 + m) * 65 + 0) * 9 + tap];
    }
}

// x padded fp32 plane with fused zero-guard: [t][b][PADPX]; every element of
// the padded-linear space is written (interior from x, guards 0) -> no memset.
__global__ void xprep(const float* __restrict__ x, float* __restrict__ xpad)
{
    const int gid = blockIdx.x * 256 + threadIdx.x;
    if (gid >= TT * BB * PADPX) return;
    const int q = gid % PADPX;
    const int tb = gid / PADPX;
    const int b = tb % BB;
    const int t = tb / BB;
    float v = 0.f;
    const int pl = q - POFF;
    if (pl >= 0) {
        const int py = pl / 50, pxx = pl - py * 50;
        if (py >= 1 && py <= 48 && pxx >= 1 && pxx <= 48)
            v = x[((size_t)b * TT + t) * HWSZ + (py - 1) * 48 + (pxx - 1)];
    }
    xpad[gid] = v;
}

// One step: L0(t) [units 0..3] and L1(t-1) [units 4..5].
// Wave = 32 px (2 B-tiles of 16) x 16 hid x 4 gates, 16x16x32, A split-bf16.
// A-slot (72 KB) staged into LDS once per block per slot-pair (8 waves share).
// 512-thread blocks, 480 grid -> 2 blocks/CU: one block's staging/barriers
// overlap the other's compute. c first use takes cp=0 via czero flags.
// 1-D grid, b = blockIdx.x & 7 -> batch pinned to one XCD.
// h buffers: [kslot6][b][PADPX][16ch], single bf16 (kslot 0-3 = h0, 4-5 = h1).
__global__ __launch_bounds__(512, 4) void mstep(
    const u16* __restrict__ in_hi,
    u16* __restrict__ out_hi,
    const float* __restrict__ xpad,
    const u16* __restrict__ wf, const float* __restrict__ wxf,
    const float* __restrict__ b0, const float* __restrict__ b1,
    float* __restrict__ cbuf, float* __restrict__ seq_t,
    int t, int doL0, int doL1, int c0z, int c1z)
{
    __shared__ __align__(16) char ldsA[73728];   // one 72 KB A-slot

    const int tid = threadIdx.x;
    const int lane = tid & 63;
    const int wv = tid >> 6;
    const int lid = blockIdx.x;
    const int b = lid & 7;           // XCD selector
    const int r = lid >> 3;
    const int unit = r % 6;
    const int pg = r / 6;
    const bool isL0 = unit < 4;
    if (isL0) { if (!doL0) return; } else { if (!doL1) return; }   // block-uniform
    const int frag = pg * 8 + wv;
    const bool active = frag < NWAVE;   // inactive waves still do staging+barriers
    const int p0 = (active ? frag : 0) * 32;
    const int hidg = isL0 ? unit : (unit - 4);
    const bool czero = isL0 ? (c0z != 0) : (c1z != 0);

    const int n   = lane & 15;        // px col within tile; also A row m
    const int khb = (lane >> 4) & 1;  // within-slot 8-ch half for B
    const int ksl = lane >> 5;        // slot parity for B
    const int mq  = lane >> 4;        // D row quarter: m = mq*4 + e

    // early c-state load (czero: first use of this layer's c -> cp = 0)
    const int slot = (unit * 8 + b) * NWAVE + (active ? frag : 0);
    float* cptr = cbuf + (size_t)slot * 512;
    const f32x4 cp0 = (active && !czero) ? *(const f32x4*)(cptr + lane * 4)
                                         : (f32x4){0.f, 0.f, 0.f, 0.f};
    const f32x4 cp1 = (active && !czero) ? *(const f32x4*)(cptr + 256 + lane * 4)
                                         : (f32x4){0.f, 0.f, 0.f, 0.f};

    // acc init = bias (D: col=lane&15, row m=mq*4+e)
    const float* bias = isL0 ? b0 : b1;
    const int CHID = isL0 ? 64 : 32;
    f32x4 acc[2][4];
    #pragma unroll
    for (int g = 0; g < 4; ++g) {
        const f32x4 bv = *(const f32x4*)(bias + g * CHID + hidg * 16 + mq * 4);
        acc[0][g] = bv;
        acc[1][g] = bv;
    }

    const size_t base0 = ((size_t)(ksl * 8 + b) * PADPX + POFF + p0 + n) * 16 + khb * 8;
    const size_t bstride = (size_t)2 * 8 * PADPX * 16;   // per slot-pair

    const int nsl = isL0 ? 2 : 3;
    const char* pa = ldsA + lane * 16;

    for (int sp = 0; sp < nsl; ++sp) {
        const u16* pbh = in_hi + base0 + (size_t)sp * bstride;
        // pre-issue B(tap 0) so its latency hides under staging + barrier
        bf16x8 Bc0 = *(const bf16x8*)(pbh + (long)(-51) * 16);
        bf16x8 Bc1 = *(const bf16x8*)(pbh + (long)(-35) * 16);

        if (sp) __syncthreads();        // previous slot's readers done
        // stage this slot's 72 KB of A fragments (coalesced, linear)
        const u16* asrc = wf + (isL0 ? (size_t)((hidg * 2 + sp) * 72) * 512
                                     : (size_t)(576 + (hidg * 3 + sp) * 72) * 512);
        #pragma unroll
        for (int i = 0; i < 9; ++i) {
            const int u = tid + 512 * i;          // 4608 x 16B units
            *(uint4*)(ldsA + (size_t)u * 16) = *(const uint4*)(asrc + (size_t)u * 8);
        }
        __syncthreads();

        #pragma unroll
        for (int tap = 0; tap < 9; ++tap) {
            bf16x8 Bn0, Bn1;
            if (tap < 8) {
                const int tap2 = tap + 1;
                const int toff2 = ((tap2 / 3) - 1) * 50 + (tap2 % 3) - 1;
                Bn0 = *(const bf16x8*)(pbh + (long)toff2 * 16);
                Bn1 = *(const bf16x8*)(pbh + (long)(toff2 + 16) * 16);
            }
            #pragma unroll
            for (int g = 0; g < 4; ++g) {
                const bf16x8 Ah = *(const bf16x8*)(pa + (size_t)(tap * 8 + g * 2 + 0) * 1024);
                const bf16x8 Al = *(const bf16x8*)(pa + (size_t)(tap * 8 + g * 2 + 1) * 1024);
                acc[0][g] = __builtin_amdgcn_mfma_f32_16x16x32_bf16(Al, Bc0, acc[0][g], 0, 0, 0);
                acc[1][g] = __builtin_amdgcn_mfma_f32_16x16x32_bf16(Al, Bc1, acc[1][g], 0, 0, 0);
                acc[0][g] = __builtin_amdgcn_mfma_f32_16x16x32_bf16(Ah, Bc0, acc[0][g], 0, 0, 0);
                acc[1][g] = __builtin_amdgcn_mfma_f32_16x16x32_bf16(Ah, Bc1, acc[1][g], 0, 0, 0);
            }
            if (tap < 8) { Bc0 = Bn0; Bc1 = Bn1; }
        }
    }

    if (isL0) {
        // ---- x channel on VALU, exact fp32 ----
        const float* xrow = xpad + (size_t)(t * BB + b) * PADPX + POFF + p0 + n;
        #pragma unroll
        for (int tap = 0; tap < 9; ++tap) {
            const int toff = ((tap / 3) - 1) * 50 + (tap % 3) - 1;
            const float xv0 = xrow[toff];
            const float xv1 = xrow[toff + 16];
            #pragma unroll
            for (int g = 0; g < 4; ++g) {
                const f32x4 wvx = *(const f32x4*)(wxf +
                    ((size_t)(tap * 4 + g) * 16 + hidg * 4 + mq) * 4);
                #pragma unroll
                for (int e = 0; e < 4; ++e) {
                    acc[0][g][e] += wvx[e] * xv0;
                    acc[1][g][e] += wvx[e] * xv1;
                }
            }
        }
    }

    if (!active) return;   // no more barriers past this point

    // ---- epilogue: LSTM pointwise; lane owns 2 px (one per tile), 4 m-rows ----
    #pragma unroll
    for (int tl = 0; tl < 2; ++tl) {
        const f32x4 cp = tl ? cp1 : cp0;
        const int p = p0 + tl * 16 + n;
        const int py = p / 50, pxx = p - py * 50;
        const bool valid = (py >= 1) && (py <= 48) && (pxx >= 1) && (pxx <= 48);
        const int pix = (py - 1) * 48 + (pxx - 1);
        const bool doseq = (!isL0) && (b == 0) && valid;
        f32x4 cn;
        s16x4 sh;
        #pragma unroll
        for (int e = 0; e < 4; ++e) {
            const float i_ = sigm(acc[tl][0][e]);
            const float f_ = sigm(acc[tl][1][e]);
            const float o_ = sigm(acc[tl][2][e]);
            const float g_ = tanhf(acc[tl][3][e]);
            const float cv = f_ * cp[e] + i_ * g_;
            const float hv = o_ * tanhf(cv);
            cn[e] = cv;
            sh[e] = (short)f2bf(hv);
            if (doseq) {
                const int ch = hidg * 16 + mq * 4 + e;
                __builtin_nontemporal_store(hv, seq_t + (size_t)ch * HWSZ + pix);
            }
        }
        *(f32x4*)(cptr + tl * 256 + lane * 4) = cn;
        if (valid) {
            const int kslot = (isL0 ? 0 : 4) + hidg;
            const size_t ob = (((size_t)kslot * 8 + b) * PADPX + POFF + p) * 16 + mq * 4;
            *(s16x4*)(out_hi + ob) = sh;
        }
    }
}

// out[k] = bl + sum_j wl[j] * seq_flat[32k+j]   (seq layout [t][32ch][2304px])
__global__ void head_kernel(const float* __restrict__ seq,
                            const float* __restrict__ wl,
                            const float* __restrict__ bl,
                            float* __restrict__ out, int nk)
{
    __shared__ float wls[32];
    if (threadIdx.x < 32) wls[threadIdx.x] = wl[threadIdx.x];
    __syncthreads();
    int k = blockIdx.x * 256 + threadIdx.x;
    if (k >= nk) return;
    const float4* p = (const float4*)(seq + (size_t)k * 32);
    float s = bl[0];
    #pragma unroll
    for (int q = 0; q < 8; ++q) {
        float4 f = p[q];
        s += f.x * wls[q * 4 + 0] + f.y * wls[q * 4 + 1]
           + f.z * wls[q * 4 + 2] + f.w * wls[q * 4 + 3];
    }
    out[k] = s;
}

extern "C" void kernel_launch(void* const* d_in, const int* in_sizes, int n_in,
                              void* d_out, int out_size, void* d_ws, size_t ws_size,
                              hipStream_t stream)
{
    const float* x  = (const float*)d_in[0];   // [8,32,1,48,48]
    const float* w0 = (const float*)d_in[1];   // [256,65,3,3]
    const float* b0 = (const float*)d_in[2];   // [256]
    const float* w1 = (const float*)d_in[3];   // [128,96,3,3]
    const float* b1 = (const float*)d_in[4];   // [128]
    const float* wl = (const float*)d_in[5];   // [1,32]
    const float* bl = (const float*)d_in[6];   // [1]
    float* out = (float*)d_out;                // [73728]

    char* p = (char*)d_ws;
    auto alloc = [&](size_t bytes) -> char* {
        char* r = p; p += (bytes + 255) & ~(size_t)255; return r;
    };
    const size_t inbytes = (size_t)6 * BB * PADPX * 16 * 2;   // 3.94 MB
    u16* inA_hi = (u16*)alloc(inbytes);
    u16* inB_hi = (u16*)alloc(inbytes);
    const size_t xbytes = (size_t)TT * BB * PADPX * 4;        // 2.75 MB
    float* xpad = (float*)alloc(xbytes);
    u16* wfall  = (u16*)alloc((size_t)1008 * 1024);           // 1.03 MB
    float* wxf  = (float*)alloc((size_t)2304 * 4);
    const size_t cbytes = (size_t)6 * BB * NWAVE * 512 * 4;   // 7.57 MB
    float* cbuf = (float*)alloc(cbytes);
    float* seq  = (float*)alloc((size_t)TT * 32 * HWSZ * 4);  // 9.44 MB

    // h guard bands must be zero once per call (interiors are rewritten
    // every step; guards are never written by mstep).
    hipMemsetAsync(inA_hi, 0, inbytes, stream);
    hipMemsetAsync(inB_hi, 0, inbytes, stream);

    wprep<<<(1008 * 64 + 2304 + 255) / 256, 256, 0, stream>>>(w0, w1, wfall, wxf);
    xprep<<<(TT * BB * PADPX + 255) / 256, 256, 0, stream>>>(x, xpad);

    for (int s = 0; s <= TT; ++s) {
        const u16* cih = (s & 1) ? inB_hi : inA_hi;
        u16* noh = (s & 1) ? inA_hi : inB_hi;
        const int tq = (s >= 1) ? (s - 1) : 0;
        mstep<<<dim3(480), 512, 0, stream>>>(
            cih, noh, xpad, wfall, wxf, b0, b1,
            cbuf, seq + (size_t)tq * 32 * HWSZ,
            (s < TT) ? s : 0, (s < TT) ? 1 : 0, (s >= 1) ? 1 : 0,
            (s == 0) ? 1 : 0, (s == 1) ? 1 : 0);
    }
    head_kernel<<<288, 256, 0, stream>>>(seq, wl, bl, out, 73728);
}

// Round 25
// 705.564 us; speedup vs baseline: 1.8394x; 1.4423x over previous
//
#include <hip/hip_runtime.h>
#include <cmath>

#define HH 48
#define WW 48
#define HWSZ 2304
#define BB 8
#define TT 32
#define PADPX 2688   // 64 guard + 2464 main + 160 guard
#define POFF 64
#define NWAVE 77     // waves of 32 px covering 2464 padded-linear px

typedef unsigned short u16;
typedef __attribute__((ext_vector_type(8))) short bf16x8;
typedef __attribute__((ext_vector_type(4))) float f32x4;
typedef __attribute__((ext_vector_type(4))) short s16x4;

__device__ __forceinline__ u16 f2bf(float f) {
    unsigned int u = __float_as_uint(f);
    u = (u + 0x7fffu + ((u >> 16) & 1u)) >> 16;
    return (u16)u;
}
__device__ __forceinline__ float bf2f(u16 s) {
    return __uint_as_float(((unsigned int)s) << 16);
}
__device__ __forceinline__ float sigm(float x) { return 1.f / (1.f + __expf(-x)); }

// ---------------- weight fragments ----------------
// A frag = 16 hid x 32 k, 1KB; lane: m = lane&15, k = (lane>>4)*8 + j.
// wf frag index space (single bf16 plane now — no hi/lo split):
//   [0,288)   : L0-h [hidg4][cs2][tap9][g4]   (w0 ic = cs*32 + k + 1)
//   [288,504) : L1   [hidg2][cs3][tap9][g4]   (w1 ic = cs*32 + k)
// wxf (fp32): [tap9][g4][mblock16][4] -> w0 ic = 0 (the x channel), m=oc row
// Weight rounding to bf16 is iid per weight -> averages across the 576-term
// gate sum (~4e-4 preact std); x-channel stays exact fp32 on VALU.
__global__ void wprep(const float* __restrict__ w0, const float* __restrict__ w1,
                      u16* __restrict__ wf, float* __restrict__ wxf)
{
    const int gid = blockIdx.x * 256 + threadIdx.x;
    if (gid < 504 * 64) {
        const int lane = gid & 63;
        const int f = gid >> 6;
        const int m = lane & 15;
        const int kh = lane >> 4;
        float v[8];
        if (f < 288) {
            const int g = f & 3;
            int r = f >> 2;
            const int tap = r % 9; r /= 9;
            const int cs = r & 1;
            const int hidg = r >> 1;
            const int oc = g * 64 + hidg * 16 + m;
            #pragma unroll
            for (int j = 0; j < 8; ++j) {
                const int ic = cs * 32 + kh * 8 + j + 1;
                v[j] = w0[((size_t)oc * 65 + ic) * 9 + tap];
            }
        } else {
            const int f2 = f - 288;
            const int g = f2 & 3;
            int r = f2 >> 2;
            const int tap = r % 9; r /= 9;
            const int cs = r % 3;
            const int hidg = r / 3;
            const int oc = g * 32 + hidg * 16 + m;
            #pragma unroll
            for (int j = 0; j < 8; ++j) {
                const int ic = cs * 32 + kh * 8 + j;
                v[j] = w1[((size_t)oc * 96 + ic) * 9 + tap];
            }
        }
        u16 o[8] __attribute__((aligned(16)));
        #pragma unroll
        for (int j = 0; j < 8; ++j) o[j] = f2bf(v[j]);
        *(uint4*)(wf + (size_t)gid * 8) = *(const uint4*)o;
    }
    const int wx = gid - 504 * 64;
    if (wx >= 0 && wx < 2304) {
        const int e = wx & 3;
        const int f4 = wx >> 2;
        const int mb = f4 & 15;
        const int tg = f4 >> 4;
        const int g = tg & 3;
        const int tap = tg >> 2;
        const int m = mb * 4 + e;
        wxf[wx] = w0[((size_t)(g * 64 + m) * 65 + 0) * 9 + tap];
    }
}

// x padded fp32 plane with fused zero-guard: [t][b][PADPX]; every element of
// the padded-linear space is written (interior from x, guards 0) -> no memset.
__global__ void xprep(const float* __restrict__ x, float* __restrict__ xpad)
{
    const int gid = blockIdx.x * 256 + threadIdx.x;
    if (gid >= TT * BB * PADPX) return;
    const int q = gid % PADPX;
    const int tb = gid / PADPX;
    const int b = tb % BB;
    const int t = tb / BB;
    float v = 0.f;
    const int pl = q - POFF;
    if (pl >= 0) {
        const int py = pl / 50, pxx = pl - py * 50;
        if (py >= 1 && py <= 48 && pxx >= 1 && pxx <= 48)
            v = x[((size_t)b * TT + t) * HWSZ + (py - 1) * 48 + (pxx - 1)];
    }
    xpad[gid] = v;
}

// One step: L0(t) [units 0..3] and L1(t-1) [units 4..5].
// Wave = 32 px (2 B-tiles of 16) x 16 hid x 4 gates, 16x16x32 bf16.
// A-slot (36 KB, single plane) staged into LDS once per block per slot-pair.
// Per tap: 4 ds_read_b128 feed 8 MFMAs. 512-thread blocks, 480 grid;
// 36 KB LDS -> up to 4 blocks/CU residency headroom for stage/compute overlap.
// c first use takes cp=0 via czero flags. b = blockIdx.x & 7 pins batch to XCD.
// h buffers: [kslot6][b][PADPX][16ch], single bf16 (kslot 0-3 = h0, 4-5 = h1).
__global__ __launch_bounds__(512, 4) void mstep(
    const u16* __restrict__ in_hi,
    u16* __restrict__ out_hi,
    const float* __restrict__ xpad,
    const u16* __restrict__ wf, const float* __restrict__ wxf,
    const float* __restrict__ b0, const float* __restrict__ b1,
    float* __restrict__ cbuf, float* __restrict__ seq_t,
    int t, int doL0, int doL1, int c0z, int c1z)
{
    __shared__ __align__(16) char ldsA[36864];   // one 36 KB A-slot

    const int tid = threadIdx.x;
    const int lane = tid & 63;
    const int wv = tid >> 6;
    const int lid = blockIdx.x;
    const int b = lid & 7;           // XCD selector
    const int r = lid >> 3;
    const int unit = r % 6;
    const int pg = r / 6;
    const bool isL0 = unit < 4;
    if (isL0) { if (!doL0) return; } else { if (!doL1) return; }   // block-uniform
    const int frag = pg * 8 + wv;
    const bool active = frag < NWAVE;   // inactive waves still do staging+barriers
    const int p0 = (active ? frag : 0) * 32;
    const int hidg = isL0 ? unit : (unit - 4);
    const bool czero = isL0 ? (c0z != 0) : (c1z != 0);

    const int n   = lane & 15;        // px col within tile; also A row m
    const int khb = (lane >> 4) & 1;  // within-slot 8-ch half for B
    const int ksl = lane >> 5;        // slot parity for B
    const int mq  = lane >> 4;        // D row quarter: m = mq*4 + e

    // early c-state load (czero: first use of this layer's c -> cp = 0)
    const int slot = (unit * 8 + b) * NWAVE + (active ? frag : 0);
    float* cptr = cbuf + (size_t)slot * 512;
    const f32x4 cp0 = (active && !czero) ? *(const f32x4*)(cptr + lane * 4)
                                         : (f32x4){0.f, 0.f, 0.f, 0.f};
    const f32x4 cp1 = (active && !czero) ? *(const f32x4*)(cptr + 256 + lane * 4)
                                         : (f32x4){0.f, 0.f, 0.f, 0.f};

    // acc init = bias (D: col=lane&15, row m=mq*4+e)
    const float* bias = isL0 ? b0 : b1;
    const int CHID = isL0 ? 64 : 32;
    f32x4 acc[2][4];
    #pragma unroll
    for (int g = 0; g < 4; ++g) {
        const f32x4 bv = *(const f32x4*)(bias + g * CHID + hidg * 16 + mq * 4);
        acc[0][g] = bv;
        acc[1][g] = bv;
    }

    const size_t base0 = ((size_t)(ksl * 8 + b) * PADPX + POFF + p0 + n) * 16 + khb * 8;
    const size_t bstride = (size_t)2 * 8 * PADPX * 16;   // per slot-pair

    const int nsl = isL0 ? 2 : 3;
    const char* pa = ldsA + lane * 16;

    for (int sp = 0; sp < nsl; ++sp) {
        const u16* pbh = in_hi + base0 + (size_t)sp * bstride;
        // pre-issue B(tap 0) so its latency hides under staging + barrier
        bf16x8 Bc0 = *(const bf16x8*)(pbh + (long)(-51) * 16);
        bf16x8 Bc1 = *(const bf16x8*)(pbh + (long)(-35) * 16);

        if (sp) __syncthreads();        // previous slot's readers done
        // stage this slot's 36 KB of A fragments (2304 x 16B, coalesced)
        const u16* asrc = wf + (isL0 ? (size_t)((hidg * 2 + sp) * 36) * 512
                                     : (size_t)(288 + (hidg * 3 + sp) * 36) * 512);
        #pragma unroll
        for (int i = 0; i < 4; ++i) {
            const int u = tid + 512 * i;
            *(uint4*)(ldsA + (size_t)u * 16) = *(const uint4*)(asrc + (size_t)u * 8);
        }
        if (tid < 256) {
            const int u = tid + 2048;
            *(uint4*)(ldsA + (size_t)u * 16) = *(const uint4*)(asrc + (size_t)u * 8);
        }
        __syncthreads();

        #pragma unroll
        for (int tap = 0; tap < 9; ++tap) {
            bf16x8 Bn0, Bn1;
            if (tap < 8) {
                const int tap2 = tap + 1;
                const int toff2 = ((tap2 / 3) - 1) * 50 + (tap2 % 3) - 1;
                Bn0 = *(const bf16x8*)(pbh + (long)toff2 * 16);
                Bn1 = *(const bf16x8*)(pbh + (long)(toff2 + 16) * 16);
            }
            #pragma unroll
            for (int g = 0; g < 4; ++g) {
                const bf16x8 Ah = *(const bf16x8*)(pa + (size_t)(tap * 4 + g) * 1024);
                acc[0][g] = __builtin_amdgcn_mfma_f32_16x16x32_bf16(Ah, Bc0, acc[0][g], 0, 0, 0);
                acc[1][g] = __builtin_amdgcn_mfma_f32_16x16x32_bf16(Ah, Bc1, acc[1][g], 0, 0, 0);
            }
            if (tap < 8) { Bc0 = Bn0; Bc1 = Bn1; }
        }
    }

    if (isL0) {
        // ---- x channel on VALU, exact fp32 ----
        const float* xrow = xpad + (size_t)(t * BB + b) * PADPX + POFF + p0 + n;
        #pragma unroll
        for (int tap = 0; tap < 9; ++tap) {
            const int toff = ((tap / 3) - 1) * 50 + (tap % 3) - 1;
            const float xv0 = xrow[toff];
            const float xv1 = xrow[toff + 16];
            #pragma unroll
            for (int g = 0; g < 4; ++g) {
                const f32x4 wvx = *(const f32x4*)(wxf +
                    ((size_t)(tap * 4 + g) * 16 + hidg * 4 + mq) * 4);
                #pragma unroll
                for (int e = 0; e < 4; ++e) {
                    acc[0][g][e] += wvx[e] * xv0;
                    acc[1][g][e] += wvx[e] * xv1;
                }
            }
        }
    }

    if (!active) return;   // no more barriers past this point

    // ---- epilogue: LSTM pointwise; lane owns 2 px (one per tile), 4 m-rows ----
    #pragma unroll
    for (int tl = 0; tl < 2; ++tl) {
        const f32x4 cp = tl ? cp1 : cp0;
        const int p = p0 + tl * 16 + n;
        const int py = p / 50, pxx = p - py * 50;
        const bool valid = (py >= 1) && (py <= 48) && (pxx >= 1) && (pxx <= 48);
        const int pix = (py - 1) * 48 + (pxx - 1);
        const bool doseq = (!isL0) && (b == 0) && valid;
        f32x4 cn;
        s16x4 sh;
        #pragma unroll
        for (int e = 0; e < 4; ++e) {
            const float i_ = sigm(acc[tl][0][e]);
            const float f_ = sigm(acc[tl][1][e]);
            const float o_ = sigm(acc[tl][2][e]);
            const float g_ = tanhf(acc[tl][3][e]);
            const float cv = f_ * cp[e] + i_ * g_;
            const float hv = o_ * tanhf(cv);
            cn[e] = cv;
            sh[e] = (short)f2bf(hv);
            if (doseq) {
                const int ch = hidg * 16 + mq * 4 + e;
                __builtin_nontemporal_store(hv, seq_t + (size_t)ch * HWSZ + pix);
            }
        }
        *(f32x4*)(cptr + tl * 256 + lane * 4) = cn;
        if (valid) {
            const int kslot = (isL0 ? 0 : 4) + hidg;
            const size_t ob = (((size_t)kslot * 8 + b) * PADPX + POFF + p) * 16 + mq * 4;
            *(s16x4*)(out_hi + ob) = sh;
        }
    }
}

// out[k] = bl + sum_j wl[j] * seq_flat[32k+j]   (seq layout [t][32ch][2304px])
__global__ void head_kernel(const float* __restrict__ seq,
                            const float* __restrict__ wl,
                            const float* __restrict__ bl,
                            float* __restrict__ out, int nk)
{
    __shared__ float wls[32];
    if (threadIdx.x < 32) wls[threadIdx.x] = wl[threadIdx.x];
    __syncthreads();
    int k = blockIdx.x * 256 + threadIdx.x;
    if (k >= nk) return;
    const float4* p = (const float4*)(seq + (size_t)k * 32);
    float s = bl[0];
    #pragma unroll
    for (int q = 0; q < 8; ++q) {
        float4 f = p[q];
        s += f.x * wls[q * 4 + 0] + f.y * wls[q * 4 + 1]
           + f.z * wls[q * 4 + 2] + f.w * wls[q * 4 + 3];
    }
    out[k] = s;
}

extern "C" void kernel_launch(void* const* d_in, const int* in_sizes, int n_in,
                              void* d_out, int out_size, void* d_ws, size_t ws_size,
                              hipStream_t stream)
{
    const float* x  = (const float*)d_in[0];   // [8,32,1,48,48]
    const float* w0 = (const float*)d_in[1];   // [256,65,3,3]
    const float* b0 = (const float*)d_in[2];   // [256]
    const float* w1 = (const float*)d_in[3];   // [128,96,3,3]
    const float* b1 = (const float*)d_in[4];   // [128]
    const float* wl = (const float*)d_in[5];   // [1,32]
    const float* bl = (const float*)d_in[6];   // [1]
    float* out = (float*)d_out;                // [73728]

    char* p = (char*)d_ws;
    auto alloc = [&](size_t bytes) -> char* {
        char* r = p; p += (bytes + 255) & ~(size_t)255; return r;
    };
    const size_t inbytes = (size_t)6 * BB * PADPX * 16 * 2;   // 3.94 MB
    u16* inA_hi = (u16*)alloc(inbytes);
    u16* inB_hi = (u16*)alloc(inbytes);
    const size_t xbytes = (size_t)TT * BB * PADPX * 4;        // 2.75 MB
    float* xpad = (float*)alloc(xbytes);
    u16* wfall  = (u16*)alloc((size_t)504 * 1024);            // 516 KB
    float* wxf  = (float*)alloc((size_t)2304 * 4);
    const size_t cbytes = (size_t)6 * BB * NWAVE * 512 * 4;   // 7.57 MB
    float* cbuf = (float*)alloc(cbytes);
    float* seq  = (float*)alloc((size_t)TT * 32 * HWSZ * 4);  // 9.44 MB

    // h guard bands must be zero once per call (interiors are rewritten
    // every step; guards are never written by mstep).
    hipMemsetAsync(inA_hi, 0, inbytes, stream);
    hipMemsetAsync(inB_hi, 0, inbytes, stream);

    wprep<<<(504 * 64 + 2304 + 255) / 256, 256, 0, stream>>>(w0, w1, wfall, wxf);
    xprep<<<(TT * BB * PADPX + 255) / 256, 256, 0, stream>>>(x, xpad);

    for (int s = 0; s <= TT; ++s) {
        const u16* cih = (s & 1) ? inB_hi : inA_hi;
        u16* noh = (s & 1) ? inA_hi : inB_hi;
        const int tq = (s >= 1) ? (s - 1) : 0;
        mstep<<<dim3(480), 512, 0, stream>>>(
            cih, noh, xpad, wfall, wxf, b0, b1,
            cbuf, seq + (size_t)tq * 32 * HWSZ,
            (s < TT) ? s : 0, (s < TT) ? 1 : 0, (s >= 1) ? 1 : 0,
            (s == 0) ? 1 : 0, (s == 1) ? 1 : 0);
    }
    head_kernel<<<288, 256, 0, stream>>>(seq, wl, bl, out, 73728);
}